// Round 3
// baseline (936.715 us; speedup 1.0000x reference)
//
#include <hip/hip_runtime.h>
#include <hip/hip_bf16.h>
#include <stdint.h>

#define B_  2048
#define T_  16
#define F_  768
#define H_  1024
#define G4_ 4096   // 4*H

typedef __attribute__((ext_vector_type(8))) __bf16 bf16x8;
typedef __attribute__((ext_vector_type(4))) float  f32x4;

static __device__ __forceinline__ unsigned short f2bf(float f) {
    union { float f; uint32_t u; } v; v.f = f;
    uint32_t u = v.u;
    uint32_t r = (u + 0x7fffu + ((u >> 16) & 1u)) >> 16;   // RNE
    return (unsigned short)r;
}
static __device__ __forceinline__ unsigned short f2h(float f) {
    union { _Float16 h; unsigned short u; } v; v.h = (_Float16)f; return v.u;
}
static __device__ __forceinline__ float h2f(unsigned short u) {
    union { _Float16 h; unsigned short u; } v; v.u = u; return (float)v.h;
}
static __device__ __forceinline__ float sigf(float x) {
    return 1.0f / (1.0f + __expf(-x));
}
static __device__ __forceinline__ float tanhfast(float x) {
    return 2.0f / (1.0f + __expf(-2.0f * x)) - 1.0f;
}

#define GLOAD_LDS16(gsrc, ldst)                                                       \
    __builtin_amdgcn_global_load_lds((const __attribute__((address_space(1))) void*)(gsrc), \
                                     (__attribute__((address_space(3))) void*)(ldst), \
                                     16, 0, 0)

// ---------------------------------------------------------------- prep kernels

__global__ void convert_x_kernel(const float* __restrict__ x,
                                 unsigned short* __restrict__ xbf, int n4) {
    int idx = blockIdx.x * blockDim.x + threadIdx.x;
    if (idx >= n4) return;
    float4 v = *(const float4*)(x + (size_t)idx * 4);
    ushort4 o;
    o.x = f2bf(v.x); o.y = f2bf(v.y); o.z = f2bf(v.z); o.w = f2bf(v.w);
    *(ushort4*)(xbf + (size_t)idx * 4) = o;
}

// W [K][4096] f32 -> Wt_perm [4096][K] bf16, gate-interleaved column order:
// original col n = gate*1024 + j ; new row n' = (j>>5)*128 + ((j>>4)&1)*64 + gate*16 + (j&15)
__global__ void transpose_w_kernel(const float* __restrict__ w,
                                   unsigned short* __restrict__ wt, int K) {
    __shared__ float tile[32][33];
    int nb = blockIdx.x * 32;
    int kb = blockIdx.y * 32;
    int tx = threadIdx.x, ty = threadIdx.y;
    #pragma unroll
    for (int i = 0; i < 32; i += 8)
        tile[ty + i][tx] = w[(size_t)(kb + ty + i) * G4_ + nb + tx];
    __syncthreads();
    #pragma unroll
    for (int i = 0; i < 32; i += 8) {
        int n = nb + ty + i;
        int g = n >> 10;
        int j = n & 1023;
        int np = (j >> 5) * 128 + ((j >> 4) & 1) * 64 + g * 16 + (j & 15);
        wt[(size_t)np * K + kb + tx] = f2bf(tile[tx][ty + i]);
    }
}

// ---------------------------------------------------------------- shared GEMM pieces
// 128x128 tile, BK=32, 4 waves (2x2), 4-deep LDS pipeline, counted vmcnt.
// LDS chunk swizzle: slot s of row r holds k-chunk (s ^ ((r&15)>>1 & 3)); the
// gload_lds source address is pre-swizzled (linear dest), ds_read applies the
// same XOR -> 2-way banks instead of 8-way.

#define STAGE_TILE(Abase, lda, Bbase, ldb, bufi, kt_) do {                          \
    int k0_ = (kt_) * 32;                                                           \
    GLOAD_LDS16(Abase + (size_t)(bm0 + r0 + lr) * (lda) + k0_ + q8,                 \
                &lds_a[bufi][(r0) * 32]);                                           \
    GLOAD_LDS16(Bbase + (size_t)(bn0 + r0 + lr) * (ldb) + k0_ + q8,                 \
                &lds_b[bufi][(r0) * 32]);                                           \
    GLOAD_LDS16(Abase + (size_t)(bm0 + r0 + 16 + lr) * (lda) + k0_ + q8,            \
                &lds_a[bufi][(r0 + 16) * 32]);                                      \
    GLOAD_LDS16(Bbase + (size_t)(bn0 + r0 + 16 + lr) * (ldb) + k0_ + q8,            \
                &lds_b[bufi][(r0 + 16) * 32]);                                      \
} while (0)

#define KLOOP_BODY(Abase, lda, Bbase, ldb, nkt_)                                    \
    for (int p = 0; p < 3 && p < (nkt_); ++p) STAGE_TILE(Abase, lda, Bbase, ldb, p, p); \
    for (int kt = 0; kt < (nkt_); ++kt) {                                           \
        const int cur = kt & 3;                                                     \
        if (kt + 3 < (nkt_)) STAGE_TILE(Abase, lda, Bbase, ldb, (kt + 3) & 3, kt + 3); \
        const int rem = (nkt_) - kt;                                                \
        if (rem > 3)        asm volatile("s_waitcnt vmcnt(12)" ::: "memory");       \
        else if (rem == 3)  asm volatile("s_waitcnt vmcnt(8)"  ::: "memory");       \
        else if (rem == 2)  asm volatile("s_waitcnt vmcnt(4)"  ::: "memory");       \
        else                asm volatile("s_waitcnt vmcnt(0)"  ::: "memory");       \
        __builtin_amdgcn_s_barrier();                                               \
        bf16x8 a_frag[4], b_frag[4];                                                \
        _Pragma("unroll")                                                           \
        for (int mi = 0; mi < 4; ++mi)                                              \
            a_frag[mi] = *(const bf16x8*)&lds_a[cur][(wr * 64 + mi * 16 + fr) * 32 + fk]; \
        _Pragma("unroll")                                                           \
        for (int ni = 0; ni < 4; ++ni)                                              \
            b_frag[ni] = *(const bf16x8*)&lds_b[cur][(wc * 64 + ni * 16 + fr) * 32 + fk]; \
        __builtin_amdgcn_s_setprio(1);                                              \
        _Pragma("unroll")                                                           \
        for (int mi = 0; mi < 4; ++mi)                                              \
            _Pragma("unroll")                                                       \
            for (int ni = 0; ni < 4; ++ni)                                          \
                acc[mi][ni] = __builtin_amdgcn_mfma_f32_16x16x32_bf16(              \
                    a_frag[mi], b_frag[ni], acc[mi][ni], 0, 0, 0);                  \
        __builtin_amdgcn_s_setprio(0);                                              \
        __builtin_amdgcn_s_barrier();                                               \
    }

// ---------------------------------------------------------------- big x-GEMM
// gx[t][b][unit][gate] (f16) = x2d[32768,768] @ Wih_perm ; grid 8192 (1D)

__global__ __launch_bounds__(256) void xgemm_kernel(
        const unsigned short* __restrict__ xbf,    // [32768][768] bf16 (m=b*16+t)
        const unsigned short* __restrict__ wih_t,  // [4096][768]  bf16 perm
        unsigned short* __restrict__ gx) {         // [16][2048][1024][4] f16
    __shared__ unsigned short lds_a[4][4096];
    __shared__ unsigned short lds_b[4][4096];

    const int bid = blockIdx.x;
    const int bsw = (bid & 7) * 1024 + (bid >> 3);   // XCD-chunked (8192%8==0)
    const int bx = bsw & 255, by = bsw >> 8;
    const int bm0 = bx * 128, bn0 = by * 128;

    const int tid  = threadIdx.x;
    const int wave = tid >> 6;
    const int lane = tid & 63;
    const int wr = wave >> 1, wc = wave & 1;
    const int r0 = wave * 32;
    const int lr = lane >> 2;
    const int q8 = ((lane & 3) ^ ((lr >> 1) & 3)) * 8;   // pre-swizzled source chunk
    const int fr = lane & 15;
    const int fq = lane >> 4;
    const int fk = (fq ^ ((fr >> 1) & 3)) * 8;           // swizzled read chunk

    f32x4 acc[4][4] = {};

    KLOOP_BODY(xbf, F_, wih_t, F_, 24)

    // epilogue: pack 4 gates -> f16x4 at gx[t][b][j]
    const int j = by * 32 + wc * 16 + fr;
    #pragma unroll
    for (int mi = 0; mi < 4; ++mi) {
        #pragma unroll
        for (int r = 0; r < 4; ++r) {
            int mrow = bm0 + wr * 64 + mi * 16 + fq * 4 + r;
            int tt = mrow & 15, bb = mrow >> 4;
            ushort4 o;
            o.x = f2h(acc[mi][0][r]);
            o.y = f2h(acc[mi][1][r]);
            o.z = f2h(acc[mi][2][r]);
            o.w = f2h(acc[mi][3][r]);
            *(ushort4*)(gx + (((size_t)tt * B_ + bb) * H_ + j) * 4) = o;
        }
    }
}

// ---------------------------------------------------------------- recurrent step
// gates = gx[t] + h_prev @ Whh_perm + bias, fused LSTM cell. grid 512 (1D).

__global__ __launch_bounds__(256) void lstm_step_kernel(
        const unsigned short* __restrict__ hprev,  // [B][H] bf16
        const unsigned short* __restrict__ whh_t,  // [4096][1024] bf16 perm
        const unsigned short* __restrict__ gx,     // [16][2048][1024][4] f16
        const float* __restrict__ bias,            // [4096] original order
        float* __restrict__ c,                     // natural-layout f32 (r/w)
        unsigned short* __restrict__ hnext,        // [B][H] bf16
        float* __restrict__ hout,                  // [B][H] f32 (last step)
        int t, int nkt, int first, int last) {
    __shared__ unsigned short lds_a[4][4096];
    __shared__ unsigned short lds_b[4][4096];

    const int bid = blockIdx.x;
    const int bsw = (bid & 7) * 64 + (bid >> 3);     // XCD-chunked (512%8==0)
    const int bx = bsw & 15, by = bsw >> 4;
    const int bm0 = bx * 128, bn0 = by * 128;

    const int tid  = threadIdx.x;
    const int wave = tid >> 6;
    const int lane = tid & 63;
    const int wr = wave >> 1, wc = wave & 1;
    const int r0 = wave * 32;
    const int lr = lane >> 2;
    const int q8 = ((lane & 3) ^ ((lr >> 1) & 3)) * 8;
    const int fr = lane & 15;
    const int fq = lane >> 4;
    const int fk = (fq ^ ((fr >> 1) & 3)) * 8;

    f32x4 acc[4][4] = {};

    KLOOP_BODY(hprev, H_, whh_t, H_, nkt)

    // ---- fused LSTM-cell epilogue
    const int j = by * 32 + wc * 16 + fr;   // hidden unit
    const float b_i = bias[j];
    const float b_f = bias[H_ + j];
    const float b_g = bias[2 * H_ + j];
    const float b_o = bias[3 * H_ + j];

    #pragma unroll
    for (int mi = 0; mi < 4; ++mi) {
        #pragma unroll
        for (int r = 0; r < 4; ++r) {
            int mrow = bm0 + wr * 64 + mi * 16 + fq * 4 + r;
            ushort4 g4 = *(const ushort4*)(gx + (((size_t)t * B_ + mrow) * H_ + j) * 4);
            float gi = acc[mi][0][r] + b_i + h2f(g4.x);
            float gf = acc[mi][1][r] + b_f + h2f(g4.y);
            float gg = acc[mi][2][r] + b_g + h2f(g4.z);
            float go = acc[mi][3][r] + b_o + h2f(g4.w);
            size_t cidx = ((size_t)bsw * 16 + mi * 4 + r) * 256 + tid;  // coalesced, step-invariant
            float cold = first ? 0.0f : c[cidx];
            float cn = sigf(gf) * cold + sigf(gi) * tanhfast(gg);
            float hv = sigf(go) * tanhfast(cn);
            c[cidx] = cn;
            hnext[(size_t)mrow * H_ + j] = f2bf(hv);
            if (last) hout[(size_t)mrow * H_ + j] = hv;
        }
    }
}

// ---------------------------------------------------------------- launch

extern "C" void kernel_launch(void* const* d_in, const int* in_sizes, int n_in,
                              void* d_out, int out_size, void* d_ws, size_t ws_size,
                              hipStream_t stream) {
    const float* x    = (const float*)d_in[0];   // [B,T,F]
    const float* Wih  = (const float*)d_in[1];   // [F,4H]
    const float* Whh  = (const float*)d_in[2];   // [H,4H]
    const float* bias = (const float*)d_in[3];   // [4H]
    float* out = (float*)d_out;                  // [B,H] flat

    char* ws = (char*)d_ws;
    unsigned short* xbf   = (unsigned short*)(ws);               // 50,331,648 B
    unsigned short* wih_t = (unsigned short*)(ws + 50331648);    //  6,291,456
    unsigned short* whh_t = (unsigned short*)(ws + 56623104);    //  8,388,608
    unsigned short* hbf0  = (unsigned short*)(ws + 65011712);    //  4,194,304
    unsigned short* hbf1  = (unsigned short*)(ws + 69206016);    //  4,194,304
    float*          c     = (float*)(ws + 73400320);             //  8,388,608
    unsigned short* gx    = (unsigned short*)(ws + 81788928);    // 268,435,456
    // total 350,224,384 B <= ws_size

    int n4 = B_ * T_ * F_ / 4;
    hipLaunchKernelGGL(convert_x_kernel, dim3((n4 + 255) / 256), dim3(256), 0, stream,
                       x, xbf, n4);
    hipLaunchKernelGGL(transpose_w_kernel, dim3(G4_ / 32, F_ / 32), dim3(32, 8), 0, stream,
                       Wih, wih_t, F_);
    hipLaunchKernelGGL(transpose_w_kernel, dim3(G4_ / 32, H_ / 32), dim3(32, 8), 0, stream,
                       Whh, whh_t, H_);

    // all-timestep input projection (bulk of FLOPs, fully parallel)
    hipLaunchKernelGGL(xgemm_kernel, dim3((B_ * T_ / 128) * (G4_ / 128)), dim3(256), 0, stream,
                       xbf, wih_t, gx);

    // recurrence: t=0 has no h/c contribution (nkt=0, first=1)
    for (int t = 0; t < T_; ++t) {
        unsigned short* hr = (t & 1) ? hbf0 : hbf1;
        unsigned short* hw = (t & 1) ? hbf1 : hbf0;
        int nkt   = (t == 0) ? 0 : 32;
        int first = (t == 0) ? 1 : 0;
        int last  = (t == T_ - 1) ? 1 : 0;
        hipLaunchKernelGGL(lstm_step_kernel, dim3((B_ / 128) * (G4_ / 128)), dim3(256), 0, stream,
                           hr, whh_t, gx, bias, c, hw, out, t, nkt, first, last);
    }
}